// Round 5
// baseline (37.127 us; speedup 1.0000x reference)
//
#include <hip/hip_runtime.h>
#include <math.h>

// R0 structure (1 row/block, 16384 blocks, float2 traffic) + nontemporal
// load/store hints: x is read-once, out/H are write-once -> stream past L2/L3.
// Nontemporal builtins need native vector types, not HIP_vector_type -> use
// a clang ext_vector float2 (nfloat2) for those accesses.
//
// Problem constants:
//   N=4096, P=4 -> B = 16384 rows
//   SMK = 567, L = 8, OUTLEN = 574, M = 64
// Output layout (flat): out (B,574,2) f32, then H (B,64,2) f32.

#define B_ROWS 16384
#define SMK    567
#define LTAPS  8
#define OUTLEN 574
#define MFFT   64

typedef float nfloat2 __attribute__((ext_vector_type(2)));

__global__ __launch_bounds__(256) void channel_kernel(
    const nfloat2* __restrict__ x,    // (B, SMK)  complex
    const float2*  __restrict__ cof,  // (B, LTAPS) complex
    nfloat2* __restrict__ out,        // (B, OUTLEN)
    nfloat2* __restrict__ H)          // (B, MFFT)
{
    // Padded signal: xs[i+7] = x[i]; xs[0..6] and xs[574..580] = 0.
    __shared__ float2 xs[OUTLEN + LTAPS - 1];  // 581 entries, ~4.6 KB

    const int b   = blockIdx.x;
    const int tid = threadIdx.x;

    const nfloat2* __restrict__ xrow = x + (size_t)b * SMK;

    // Zero the 14 pad slots (7 front, 7 back).
    if (tid < 2 * (LTAPS - 1)) {
        int idx = (tid < LTAPS - 1) ? tid : (OUTLEN + tid - (LTAPS - 1));
        xs[idx] = make_float2(0.0f, 0.0f);
    }
    // Stage the row (coalesced 8B nontemporal loads -> no L2/L3 pollution).
    for (int i = tid; i < SMK; i += 256) {
        nfloat2 v = __builtin_nontemporal_load(&xrow[i]);
        xs[i + (LTAPS - 1)] = make_float2(v.x, v.y);
    }

    // Taps -> registers (cof is ~1MB, leave cached).
    const float2* __restrict__ crow = cof + (size_t)b * LTAPS;
    float2 h[LTAPS];
    #pragma unroll
    for (int j = 0; j < LTAPS; ++j) h[j] = crow[j];

    __syncthreads();

    // FIR: each thread does up to 3 outputs (574 / 256).
    nfloat2* __restrict__ orow = out + (size_t)b * OUTLEN;
    #pragma unroll
    for (int it = 0; it < 3; ++it) {
        int i = tid + it * 256;
        if (i < OUTLEN) {
            float sr = 0.0f, si = 0.0f;
            #pragma unroll
            for (int j = 0; j < LTAPS; ++j) {
                float2 xv = xs[i - j + (LTAPS - 1)];
                sr = fmaf(h[j].x, xv.x, sr);
                sr = fmaf(-h[j].y, xv.y, sr);
                si = fmaf(h[j].x, xv.y, si);
                si = fmaf(h[j].y, xv.x, si);
            }
            nfloat2 o; o.x = sr; o.y = si;
            __builtin_nontemporal_store(o, &orow[i]);
        }
    }

    // 64-point DFT of the 8 taps: threads 0..63 each own one k.
    if (tid < MFFT) {
        const int k = tid;
        float accr = 0.0f, acci = 0.0f;
        #pragma unroll
        for (int l = 0; l < LTAPS; ++l) {
            int t = (k * l) & (MFFT - 1);
            float ang = -6.2831853071795864769f * (float)t * (1.0f / (float)MFFT);
            float s, c;
            __sincosf(ang, &s, &c);
            accr = fmaf(h[l].x, c, accr);
            accr = fmaf(-h[l].y, s, accr);
            acci = fmaf(h[l].x, s, acci);
            acci = fmaf(h[l].y, c, acci);
        }
        nfloat2 hv; hv.x = accr; hv.y = acci;
        __builtin_nontemporal_store(hv, &H[(size_t)b * MFFT + k]);
    }
}

extern "C" void kernel_launch(void* const* d_in, const int* in_sizes, int n_in,
                              void* d_out, int out_size, void* d_ws, size_t ws_size,
                              hipStream_t stream) {
    const nfloat2* x   = (const nfloat2*)d_in[0];  // (N,P,SMK,2) f32
    const float2*  cof = (const float2*)d_in[1];   // (N,P,L,2)  f32
    float* outf = (float*)d_out;

    nfloat2* conv_out = (nfloat2*)outf;                                  // (B, 574)
    nfloat2* H        = (nfloat2*)(outf + (size_t)B_ROWS * OUTLEN * 2);  // (B, 64)

    channel_kernel<<<B_ROWS, 256, 0, stream>>>(x, cof, conv_out, H);
}

// Round 6
// 33.992 us; speedup vs baseline: 1.0922x; 1.0922x over previous
//
#include <hip/hip_runtime.h>
#include <math.h>

// Wave-per-row structure: 256-thread block = 4 independent waves, each wave
// stages + convolves ONE row in its private LDS slice. No __syncthreads():
// same-wave LDS producer->consumer is ordered by s_waitcnt vmcnt(0) lgkmcnt(0)
// (inline asm with memory clobber). Waves drift past each other, overlapping
// staging loads of one row with compute/stores of another.
//
// Problem constants:
//   N=4096, P=4 -> B = 16384 rows; 4 rows/block -> 4096 blocks
//   SMK = 567, L = 8, OUTLEN = 574, M = 64
// Output layout (flat): out (B,574,2) f32, then H (B,64,2) f32.

#define B_ROWS 16384
#define SMK    567
#define LTAPS  8
#define OUTLEN 574
#define MFFT   64
#define PADS   (LTAPS - 1)          // 7
#define XSLEN  (OUTLEN + PADS)      // 581

__global__ __launch_bounds__(256) void channel_kernel(
    const float2* __restrict__ x,    // (B, SMK)  complex as float2
    const float2* __restrict__ cof,  // (B, LTAPS) complex as float2
    float2* __restrict__ out,        // (B, OUTLEN)
    float2* __restrict__ H)          // (B, MFFT)
{
    __shared__ float2 xs[4][XSLEN];  // one 581-entry slice per wave (~18.6 KB)

    const int wave = threadIdx.x >> 6;
    const int lane = threadIdx.x & 63;
    const int b    = blockIdx.x * 4 + wave;   // this wave's row

    float2* __restrict__ s = xs[wave];
    const float2* __restrict__ xrow = x + (size_t)b * SMK;

    // Zero the 14 pad slots (7 front, 7 back).
    if (lane < 2 * PADS) {
        int idx = (lane < PADS) ? lane : (OUTLEN + lane - PADS);
        s[idx] = make_float2(0.0f, 0.0f);
    }
    // Stage the row (coalesced 8B loads, 9 iters of 64 lanes).
    for (int i = lane; i < SMK; i += 64) {
        s[i + PADS] = xrow[i];
    }

    // Taps -> registers (broadcast-ish; cof is ~1MB, L2-resident).
    const float2* __restrict__ crow = cof + (size_t)b * LTAPS;
    float2 h[LTAPS];
    #pragma unroll
    for (int j = 0; j < LTAPS; ++j) h[j] = crow[j];

    // Same-wave fence: all global loads landed in LDS/regs before ds_reads.
    asm volatile("s_waitcnt vmcnt(0) lgkmcnt(0)" ::: "memory");

    // FIR: each lane does up to 9 outputs (574 / 64).
    float2* __restrict__ orow = out + (size_t)b * OUTLEN;
    #pragma unroll
    for (int it = 0; it < 9; ++it) {
        int i = lane + it * 64;
        if (i < OUTLEN) {
            float sr = 0.0f, si = 0.0f;
            #pragma unroll
            for (int j = 0; j < LTAPS; ++j) {
                float2 xv = s[i - j + PADS];
                sr = fmaf(h[j].x, xv.x, sr);
                sr = fmaf(-h[j].y, xv.y, sr);
                si = fmaf(h[j].x, xv.y, si);
                si = fmaf(h[j].y, xv.x, si);
            }
            orow[i] = make_float2(sr, si);
        }
    }

    // 64-point DFT of the 8 taps: each lane owns one k.
    {
        const int k = lane;
        float accr = 0.0f, acci = 0.0f;
        #pragma unroll
        for (int l = 0; l < LTAPS; ++l) {
            int t = (k * l) & (MFFT - 1);
            float ang = -6.2831853071795864769f * (float)t * (1.0f / (float)MFFT);
            float sn, cs;
            __sincosf(ang, &sn, &cs);
            accr = fmaf(h[l].x, cs, accr);
            accr = fmaf(-h[l].y, sn, accr);
            acci = fmaf(h[l].x, sn, acci);
            acci = fmaf(h[l].y, cs, acci);
        }
        H[(size_t)b * MFFT + k] = make_float2(accr, acci);
    }
}

extern "C" void kernel_launch(void* const* d_in, const int* in_sizes, int n_in,
                              void* d_out, int out_size, void* d_ws, size_t ws_size,
                              hipStream_t stream) {
    const float2* x   = (const float2*)d_in[0];  // (N,P,SMK,2) f32
    const float2* cof = (const float2*)d_in[1];  // (N,P,L,2)  f32
    float* outf = (float*)d_out;

    float2* conv_out = (float2*)outf;                                  // (B, 574)
    float2* H        = (float2*)(outf + (size_t)B_ROWS * OUTLEN * 2);  // (B, 64)

    channel_kernel<<<B_ROWS / 4, 256, 0, stream>>>(x, cof, conv_out, H);
}

// Round 7
// 32.988 us; speedup vs baseline: 1.1255x; 1.0305x over previous
//
#include <hip/hip_runtime.h>
#include <math.h>

// Persistent 2-phase pipeline (T3 minimum + T14 reg-staging):
//   2048 blocks x 256 threads (exactly 8 blocks/CU x 256 CU), each block owns
//   8 rows (strided: row = t*2048 + blockIdx.x). Double-buffered LDS row.
//   Per iteration: issue next-row global loads to REGS early -> compute
//   current row from LDS (+stores) -> ds_write staged regs to other buffer
//   -> barrier. HBM latency hides under the compute+store phase.
//
// Problem constants:
//   N=4096, P=4 -> B = 16384 rows
//   SMK = 567, L = 8, OUTLEN = 574, M = 64
// Output layout (flat): out (B,574,2) f32, then H (B,64,2) f32.
//
// LDS signal layout: xs[buf][8 + i] = x[i]; head pads [0..7] = 0,
// tail pads [575..581] = 0 (zeroed ONCE in prologue; rows only overwrite
// the interior). out[i] = sum_j h[j]*x[i-j] reads xs[i+1 .. i+8].

#define B_ROWS 16384
#define SMK    567
#define LTAPS  8
#define OUTLEN 574
#define MFFT   64
#define XSLEN  582            // 8 head + 567 + 7 tail
#define GRID   2048
#define RPB    8              // rows per block

__global__ __launch_bounds__(256) void channel_kernel(
    const float2* __restrict__ x,    // (B, SMK)
    const float2* __restrict__ cof,  // (B, LTAPS)
    float2* __restrict__ out,        // (B, OUTLEN)
    float2* __restrict__ H)          // (B, MFFT)
{
    __shared__ float2 xs[2][XSLEN];
    __shared__ float2 hs[2][LTAPS];

    const int tid = threadIdx.x;
    const int g   = blockIdx.x;
    const bool has2 = (tid + 512) < SMK;   // tid < 55

    // --- zero pads of BOTH buffers (once) ---
    if (tid < 30) {
        int bsel = tid / 15, p = tid % 15;
        int idx = (p < 8) ? p : (SMK + p);  // 575..581 for p >= 8
        xs[bsel][idx] = make_float2(0.0f, 0.0f);
    }

    // --- prologue: stage row (t=0) into buffer 0 ---
    {
        const float2* __restrict__ xrow = x + (size_t)g * SMK;
        float2 v0 = xrow[tid];
        float2 v1 = xrow[tid + 256];
        float2 v2 = has2 ? xrow[tid + 512] : make_float2(0.f, 0.f);
        xs[0][8 + tid]       = v0;
        xs[0][8 + tid + 256] = v1;
        if (has2) xs[0][8 + tid + 512] = v2;
        if (tid < LTAPS) hs[0][tid] = cof[(size_t)g * LTAPS + tid];
    }
    __syncthreads();

    int cur = 0;
    for (int t = 0; t < RPB; ++t) {
        const size_t row = (size_t)t * GRID + g;

        // --- 1) issue next row's staging loads (regs) ---
        float2 v0, v1, v2, hv;
        if (t + 1 < RPB) {
            const size_t nrow = (size_t)(t + 1) * GRID + g;
            const float2* __restrict__ xn = x + nrow * SMK;
            v0 = xn[tid];
            v1 = xn[tid + 256];
            if (has2) v2 = xn[tid + 512];
            if (tid < LTAPS) hv = cof[nrow * LTAPS + tid];
        }

        // --- 2) compute current row from xs[cur] ---
        const float2* __restrict__ s = xs[cur];
        float2 h[LTAPS];
        #pragma unroll
        for (int j = 0; j < LTAPS; ++j) h[j] = hs[cur][j];

        float2* __restrict__ orow = out + row * OUTLEN;
        #pragma unroll
        for (int it = 0; it < 3; ++it) {
            int i = tid + it * 256;
            if (i < OUTLEN) {
                float sr = 0.0f, si = 0.0f;
                #pragma unroll
                for (int j = 0; j < LTAPS; ++j) {
                    float2 xv = s[i - j + 8];
                    sr = fmaf(h[j].x, xv.x, sr);
                    sr = fmaf(-h[j].y, xv.y, sr);
                    si = fmaf(h[j].x, xv.y, si);
                    si = fmaf(h[j].y, xv.x, si);
                }
                orow[i] = make_float2(sr, si);
            }
        }

        // 64-point DFT of the 8 taps: threads 0..63 own one k each.
        if (tid < MFFT) {
            const int k = tid;
            float accr = 0.0f, acci = 0.0f;
            #pragma unroll
            for (int l = 0; l < LTAPS; ++l) {
                int tt = (k * l) & (MFFT - 1);
                float ang = -6.2831853071795864769f * (float)tt * (1.0f / (float)MFFT);
                float sn, cs;
                __sincosf(ang, &sn, &cs);
                accr = fmaf(h[l].x, cs, accr);
                accr = fmaf(-h[l].y, sn, accr);
                acci = fmaf(h[l].x, sn, acci);
                acci = fmaf(h[l].y, cs, acci);
            }
            H[row * MFFT + k] = make_float2(accr, acci);
        }

        // --- 3) commit staged regs into the other buffer, flip ---
        if (t + 1 < RPB) {
            int nxt = cur ^ 1;
            xs[nxt][8 + tid]       = v0;
            xs[nxt][8 + tid + 256] = v1;
            if (has2) xs[nxt][8 + tid + 512] = v2;
            if (tid < LTAPS) hs[nxt][tid] = hv;
            cur = nxt;
        }
        __syncthreads();
    }
}

extern "C" void kernel_launch(void* const* d_in, const int* in_sizes, int n_in,
                              void* d_out, int out_size, void* d_ws, size_t ws_size,
                              hipStream_t stream) {
    const float2* x   = (const float2*)d_in[0];  // (N,P,SMK,2) f32
    const float2* cof = (const float2*)d_in[1];  // (N,P,L,2)  f32
    float* outf = (float*)d_out;

    float2* conv_out = (float2*)outf;                                  // (B, 574)
    float2* H        = (float2*)(outf + (size_t)B_ROWS * OUTLEN * 2);  // (B, 64)

    channel_kernel<<<GRID, 256, 0, stream>>>(x, cof, conv_out, H);
}

// Round 8
// 31.046 us; speedup vs baseline: 1.1959x; 1.0625x over previous
//
#include <hip/hip_runtime.h>
#include <math.h>

// R0 block structure (1 row/block, 16384 blocks, barrier) but with the LDS
// read traffic cut ~7x: signal staged SoA (xr/xi float arrays), each FIR
// thread computes 4 CONSECUTIVE outputs from a 12-float register window
// loaded as 3 ds_read_b128 per array (lane stride 16B = the conflict-free
// max-BW LDS pattern). R0 issued 8 ds_read_b64 PER OUTPUT (~32k cy/CU of
// LDS-pipe occupancy); this issues 6 b128 per 4 outputs (~10k cy/CU).
// The 64-point tap DFT runs on wave 3 concurrently with FIR (waves 0-2).
//
// Problem constants:
//   N=4096, P=4 -> B = 16384 rows
//   SMK = 567, L = 8, OUTLEN = 574, M = 64
// Output layout (flat): out (B,574,2) f32, then H (B,64,2) f32.
//
// LDS layout: xr[8+i] = Re x[i] (i in [0,566]), head pads [0..7]=0,
// tail pads [575..591]=0. Window for outputs i0..i0+3 (i0=4t) reads float
// indices [i0-8 .. i0+3] = xr[i0 .. i0+11]: 3 aligned float4 each array.
// Output o=i0+p needs x[i0+p-j] -> window slot 8+p-j in [1..11].

#define B_ROWS 16384
#define SMK    567
#define LTAPS  8
#define OUTLEN 574
#define MFFT   64
#define XL     592   // 8 head + 567 + 17 tail

__global__ __launch_bounds__(256) void channel_kernel(
    const float2* __restrict__ x,    // (B, SMK)
    const float2* __restrict__ cof,  // (B, LTAPS)
    float2* __restrict__ out,        // (B, OUTLEN)
    float2* __restrict__ H)          // (B, MFFT)
{
    __shared__ float xr[XL];
    __shared__ float xi[XL];

    const int b   = blockIdx.x;
    const int tid = threadIdx.x;

    const float2* __restrict__ xrow = x + (size_t)b * SMK;

    // Zero pads: slots [0..7] and [575..591] in each array (25 slots).
    if (tid < 25) {
        int idx = (tid < 8) ? tid : (SMK + tid);   // tid=8 -> 575 ... tid=24 -> 591
        xr[idx] = 0.0f;
        xi[idx] = 0.0f;
    }
    // Stage row as SoA (contiguous b32 writes, free 2-way).
    for (int i = tid; i < SMK; i += 256) {
        float2 v = xrow[i];
        xr[8 + i] = v.x;
        xi[8 + i] = v.y;
    }

    // Taps (L1-broadcast; needed by FIR and DFT threads).
    const float2* __restrict__ crow = cof + (size_t)b * LTAPS;
    float2 h[LTAPS];
    #pragma unroll
    for (int j = 0; j < LTAPS; ++j) h[j] = crow[j];

    __syncthreads();

    if (tid < 144) {
        // FIR: 4 consecutive outputs per thread (thread 143 stores only 2).
        const int i0 = 4 * tid;

        // 12-float window per array: 3 aligned ds_read_b128 each.
        float4 a0 = *(const float4*)&xr[i0];
        float4 a1 = *(const float4*)&xr[i0 + 4];
        float4 a2 = *(const float4*)&xr[i0 + 8];
        float4 c0 = *(const float4*)&xi[i0];
        float4 c1 = *(const float4*)&xi[i0 + 4];
        float4 c2 = *(const float4*)&xi[i0 + 8];
        float wr[12] = {a0.x, a0.y, a0.z, a0.w, a1.x, a1.y, a1.z, a1.w,
                        a2.x, a2.y, a2.z, a2.w};
        float wi[12] = {c0.x, c0.y, c0.z, c0.w, c1.x, c1.y, c1.z, c1.w,
                        c2.x, c2.y, c2.z, c2.w};

        float sr[4] = {0.f, 0.f, 0.f, 0.f};
        float si[4] = {0.f, 0.f, 0.f, 0.f};
        #pragma unroll
        for (int j = 0; j < LTAPS; ++j) {
            float hr = h[j].x, hi = h[j].y;
            #pragma unroll
            for (int p = 0; p < 4; ++p) {
                float ar = wr[8 + p - j], ai = wi[8 + p - j];
                sr[p] = fmaf(hr, ar, sr[p]);
                sr[p] = fmaf(-hi, ai, sr[p]);
                si[p] = fmaf(hr, ai, si[p]);
                si[p] = fmaf(hi, ar, si[p]);
            }
        }

        float2* __restrict__ orow = out + (size_t)b * OUTLEN;
        *(float4*)&orow[i0] = make_float4(sr[0], si[0], sr[1], si[1]);
        if (i0 + 2 < OUTLEN) {   // skipped only by thread 143 (i0=572)
            *(float4*)&orow[i0 + 2] = make_float4(sr[2], si[2], sr[3], si[3]);
        }
    } else if (tid >= 192) {
        // 64-point DFT of the 8 taps on wave 3 (concurrent with FIR waves).
        const int k = tid - 192;
        float accr = 0.0f, acci = 0.0f;
        #pragma unroll
        for (int l = 0; l < LTAPS; ++l) {
            int t = (k * l) & (MFFT - 1);
            float ang = -6.2831853071795864769f * (float)t * (1.0f / (float)MFFT);
            float sn, cs;
            __sincosf(ang, &sn, &cs);
            accr = fmaf(h[l].x, cs, accr);
            accr = fmaf(-h[l].y, sn, accr);
            acci = fmaf(h[l].x, sn, acci);
            acci = fmaf(h[l].y, cs, acci);
        }
        H[(size_t)b * MFFT + k] = make_float2(accr, acci);
    }
}

extern "C" void kernel_launch(void* const* d_in, const int* in_sizes, int n_in,
                              void* d_out, int out_size, void* d_ws, size_t ws_size,
                              hipStream_t stream) {
    const float2* x   = (const float2*)d_in[0];  // (N,P,SMK,2) f32
    const float2* cof = (const float2*)d_in[1];  // (N,P,L,2)  f32
    float* outf = (float*)d_out;

    float2* conv_out = (float2*)outf;                                  // (B, 574)
    float2* H        = (float2*)(outf + (size_t)B_ROWS * OUTLEN * 2);  // (B, 64)

    channel_kernel<<<B_ROWS, 256, 0, stream>>>(x, cof, conv_out, H);
}